// Round 5
// baseline (807.695 us; speedup 1.0000x reference)
//
#include <hip/hip_runtime.h>
#include <hip/hip_bf16.h>

// Problem constants (B=2, S=1024, D=1024, F=4096, E=8)
#define T_TOK 2048
#define DD 1024
#define FF 4096
#define EE 8
#define MARGIN 3e-4f
#define MAXFLAG 1024

typedef __attribute__((ext_vector_type(8))) short short8;
typedef __attribute__((ext_vector_type(4))) float floatx4;
typedef unsigned short u16;
typedef unsigned int u32;

// fp32 -> bf16 RNE, raw u16
static __device__ __forceinline__ u32 f2bf_u(float f){
  u32 u = __float_as_uint(f);
  u32 r = u + 0x7fffu + ((u >> 16) & 1u);
  return r >> 16;
}
static __device__ __forceinline__ float bf2f(u32 h){
  return __uint_as_float(h << 16);
}

// async global->LDS, 16B per lane; LDS dest = wave-uniform base + lane*16
static __device__ __forceinline__ void gload16(const void* g, void* l){
  __builtin_amdgcn_global_load_lds(
      (const __attribute__((address_space(1))) void*)g,
      (__attribute__((address_space(3))) void*)l, 16, 0, 0);
}

// ---------------------------------------------------------------------------
// P1: split X into xh=bf16(X), xl=bf16(X-xh). One block per token row.
// Also zeroes nflag (stream-ordered before any consumer).
// ---------------------------------------------------------------------------
__global__ __launch_bounds__(256) void split_x(const float* __restrict__ X,
    u16* __restrict__ xh, u16* __restrict__ xl, int* nflag)
{
  if (blockIdx.x == 0 && threadIdx.x == 0) *nflag = 0;
  size_t i = (size_t)blockIdx.x * DD + threadIdx.x * 4;
  float4 v = *(const float4*)(X + i);
  u32 h0 = f2bf_u(v.x), h1 = f2bf_u(v.y), h2 = f2bf_u(v.z), h3 = f2bf_u(v.w);
  u32 l0 = f2bf_u(v.x - bf2f(h0)), l1 = f2bf_u(v.y - bf2f(h1));
  u32 l2 = f2bf_u(v.z - bf2f(h2)), l3 = f2bf_u(v.w - bf2f(h3));
  *(uint2*)(xh + i) = make_uint2(h0 | (h1 << 16), h2 | (h3 << 16));
  *(uint2*)(xl + i) = make_uint2(l0 | (l1 << 16), l2 | (l3 << 16));
}

// ---------------------------------------------------------------------------
// P2: router w1 [1024 k][1024 n] -> B3 [1024 n][3072 k] bf16 = [w1h | w1l | w1h]
// (A concat [xh | xh | xl] => xh@w1h + xh@w1l + xl@w1h ~ fp32 X@w1)
// ---------------------------------------------------------------------------
__global__ __launch_bounds__(256) void split_w1t(const float* __restrict__ w1,
                                                 u16* __restrict__ B3)
{
  __shared__ float tile[64][65];
  const int k0 = blockIdx.y * 64, n0 = blockIdx.x * 64;
  const int tc = threadIdx.x & 15, tr = threadIdx.x >> 4;
  #pragma unroll
  for (int i = 0; i < 4; ++i){
    int r = tr + 16 * i;
    float4 v = *(const float4*)(w1 + (size_t)(k0 + r) * DD + n0 + tc * 4);
    tile[r][tc*4+0] = v.x; tile[r][tc*4+1] = v.y;
    tile[r][tc*4+2] = v.z; tile[r][tc*4+3] = v.w;
  }
  __syncthreads();
  #pragma unroll
  for (int i = 0; i < 4; ++i){
    int nn = tr + 16 * i;
    u32 hh[4], ll[4];
    #pragma unroll
    for (int j = 0; j < 4; ++j){
      float v = tile[tc*4 + j][nn];
      hh[j] = f2bf_u(v);
      ll[j] = f2bf_u(v - bf2f(hh[j]));
    }
    uint2 ph = make_uint2(hh[0] | (hh[1] << 16), hh[2] | (hh[3] << 16));
    uint2 pl = make_uint2(ll[0] | (ll[1] << 16), ll[2] | (ll[3] << 16));
    u16* o = B3 + (size_t)(n0 + nn) * 3072 + k0 + tc * 4;
    *(uint2*)(o)        = ph;
    *(uint2*)(o + 1024) = pl;
    *(uint2*)(o + 2048) = ph;
  }
}

// ---------------------------------------------------------------------------
// P3/P4: expert weight transpose+convert: W [E][K][N] fp32 -> Wt [E][N][K] bf16
// ---------------------------------------------------------------------------
__global__ __launch_bounds__(256) void transpose_w(const float* __restrict__ Win,
    u16* __restrict__ Wt, int K, int N)
{
  __shared__ float tile[64][65];
  const size_t eo = (size_t)blockIdx.z * K * N;
  const int k0 = blockIdx.y * 64, n0 = blockIdx.x * 64;
  const int tc = threadIdx.x & 15, tr = threadIdx.x >> 4;
  #pragma unroll
  for (int i = 0; i < 4; ++i){
    int r = tr + 16 * i;
    float4 v = *(const float4*)(Win + eo + (size_t)(k0 + r) * N + n0 + tc * 4);
    tile[r][tc*4+0] = v.x; tile[r][tc*4+1] = v.y;
    tile[r][tc*4+2] = v.z; tile[r][tc*4+3] = v.w;
  }
  __syncthreads();
  #pragma unroll
  for (int i = 0; i < 4; ++i){
    int nn = tr + 16 * i;
    u32 p[4];
    #pragma unroll
    for (int j = 0; j < 4; ++j) p[j] = f2bf_u(tile[tc*4 + j][nn]);
    *(uint2*)(Wt + eo + (size_t)(n0 + nn) * K + k0 + tc * 4)
        = make_uint2(p[0] | (p[1] << 16), p[2] | (p[3] << 16));
  }
}

// ---------------------------------------------------------------------------
// Unified bf16 MFMA GEMM, m97-style async staging (global_load_lds, dbuf,
// one barrier per K-step; LDS frag-major so staging IS the fragment layout).
// MODE 0: H = relu([xh|xh|xl] @ B3^T + b1)      M=2048 N=1024 K=3072, fp32 out
// MODE 1: hid = relu(gather(xh,perm) @ W1t^T + b1[e]),  bf16 out, K=1024 N=4096
// MODE 2: out[perm] = hid @ W2t^T + b2[e],      fp32 scatter, K=4096 N=1024
// BM=128; BN=128 (MODE0/1) or 64 (MODE2). 4 waves 2x2; wave-tile 64 x BN/2.
// Grid y MUST cover T_TOK/128 per expert (R4 lesson: expert counts are NOT
// ~Binomial(1/8) — relu mean + fixed random w2 biases argmax; hot expert can
// take 500-800 tokens. y=4 capped at 512 and silently dropped tokens).
// ---------------------------------------------------------------------------
template<int MODE>
__global__ __launch_bounds__(256) void gemm_bf16(
    const u16* __restrict__ Abase,   // MODE0/1: xh, MODE2: hid
    const u16* __restrict__ Abase2,  // MODE0: xl, else unused
    const u16* __restrict__ Wt,      // [N][K] bf16 rows (per-expert via z)
    const float* __restrict__ bias,
    float* __restrict__ outF,
    u16* __restrict__ outH,
    const int* __restrict__ perm,
    const int* __restrict__ offsets)
{
  constexpr int K   = MODE == 0 ? 3072 : (MODE == 1 ? DD : FF);
  constexpr int AS  = MODE == 2 ? FF : DD;   // A row stride (shorts)
  constexpr int N   = MODE == 1 ? FF : DD;
  constexpr int BN  = MODE == 2 ? 64 : 128;
  constexpr int NIT = K / 32;
  constexpr int NBF = BN / 16;   // B frags per tile (8 or 4)
  constexpr int JW  = NBF / 2;   // B frags per wave (4 or 2)
  constexpr int NBW = BN == 128 ? 2 : 1;  // B staging instrs per wave

  int off, cnt;
  if constexpr (MODE == 0){ off = 0; cnt = T_TOK; }
  else {
    int e = blockIdx.z;
    off = offsets[e]; cnt = offsets[e+1] - off;
  }
  const int m0 = blockIdx.y * 128;
  if constexpr (MODE != 0){ if (m0 >= cnt) return; }
  const int nb = blockIdx.x * BN;
  const u16* W = Wt;
  const float* bs = bias;
  if constexpr (MODE != 0){
    W  = Wt + (size_t)blockIdx.z * N * K;
    bs = bias + (size_t)blockIdx.z * N;
  }

  __shared__ u16 As[2][8 * 512];
  __shared__ u16 Bs[2][NBF * 512];

  const int tid = threadIdx.x, w = tid >> 6, lane = tid & 63;
  const int lrow = lane & 15, lq = lane >> 4;
  const int wm = w & 1, wn = w >> 1;

  // per-lane staging source pointers (A frags 2w,2w+1; B frags 2w,2w+1 or w)
  const u16* aP[2]; const u16* aP2[2]; const u16* bP[NBW];
  #pragma unroll
  for (int i = 0; i < 2; ++i){
    int f = 2 * w + i;
    int m = m0 + f * 16 + lrow;
    int row;
    if constexpr (MODE == 0) row = m;
    else if constexpr (MODE == 1) row = perm[off + (m < cnt ? m : cnt - 1)];
    else row = off + (m < cnt ? m : cnt - 1);
    aP[i] = Abase + (size_t)row * AS + lq * 8;
    if constexpr (MODE == 0) aP2[i] = Abase2 + (size_t)row * AS + lq * 8;
  }
  #pragma unroll
  for (int i = 0; i < NBW; ++i){
    int f = (BN == 128) ? 2 * w + i : w;
    int n = nb + f * 16 + lrow;
    bP[i] = W + (size_t)n * K + lq * 8;
  }

  floatx4 acc[4][JW];
  #pragma unroll
  for (int i = 0; i < 4; ++i)
    #pragma unroll
    for (int j = 0; j < JW; ++j)
      acc[i][j] = (floatx4){0.f, 0.f, 0.f, 0.f};

  auto stage = [&](int buf, int kt){
    #pragma unroll
    for (int i = 0; i < 2; ++i){
      const u16* g;
      if constexpr (MODE == 0)
        g = (kt < 1024) ? aP[i] + kt
          : (kt < 2048) ? aP[i] + (kt - 1024)
                        : aP2[i] + (kt - 2048);
      else g = aP[i] + kt;
      gload16(g, &As[buf][(2 * w + i) * 512]);
    }
    #pragma unroll
    for (int i = 0; i < NBW; ++i){
      int f = (BN == 128) ? 2 * w + i : w;
      gload16(bP[i] + kt, &Bs[buf][f * 512]);
    }
  };

  auto compute = [&](int buf){
    short8 af[4], bf[JW];
    #pragma unroll
    for (int i = 0; i < 4; ++i)
      af[i] = *(const short8*)&As[buf][(wm * 4 + i) * 512 + lane * 8];
    #pragma unroll
    for (int j = 0; j < JW; ++j)
      bf[j] = *(const short8*)&Bs[buf][(wn * JW + j) * 512 + lane * 8];
    #pragma unroll
    for (int i = 0; i < 4; ++i)
      #pragma unroll
      for (int j = 0; j < JW; ++j)
        acc[i][j] = __builtin_amdgcn_mfma_f32_16x16x32_bf16(af[i], bf[j], acc[i][j], 0, 0, 0);
  };

  stage(0, 0);
  __syncthreads();
  for (int it = 0; it < NIT; ++it){
    if (it + 1 < NIT) stage((it + 1) & 1, (it + 1) * 32);
    compute(it & 1);
    __syncthreads();
  }

  // epilogue: C/D layout col=lane&15, row=quad*4+reg (verified)
  #pragma unroll
  for (int i = 0; i < 4; ++i){
    const int mloc = m0 + wm * 64 + i * 16 + lq * 4;
    #pragma unroll
    for (int j = 0; j < JW; ++j){
      const int n = nb + wn * (16 * JW) + j * 16 + lrow;
      const float bv = bs[n];
      #pragma unroll
      for (int r = 0; r < 4; ++r){
        const int m = mloc + r;
        float v = acc[i][j][r] + bv;
        if constexpr (MODE == 0){
          outF[(size_t)m * N + n] = fmaxf(v, 0.f);
        } else if constexpr (MODE == 1){
          if (m < cnt) outH[(size_t)(off + m) * FF + n] = (u16)f2bf_u(fmaxf(v, 0.f));
        } else {
          if (m < cnt) outF[(size_t)perm[off + m] * DD + n] = v;
        }
      }
    }
  }
}

// ---------------------------------------------------------------------------
// Router layer 2 + argmax from fp32 H (softmax monotone -> skip). One wave per
// token. Tokens with top1-top2 gap < MARGIN flagged for exact fp32 recompute.
// ---------------------------------------------------------------------------
__global__ __launch_bounds__(64) void logits_argmax(
    const float* __restrict__ H, const float* __restrict__ W2,
    const float* __restrict__ b2, int* __restrict__ eidx,
    int* __restrict__ flagged, int* __restrict__ nflag)
{
  const int t = blockIdx.x;
  const int lane = threadIdx.x;
  const float* h = H + (size_t)t * DD;
  float acc[8] = {0,0,0,0,0,0,0,0};
  for (int d = lane; d < DD; d += 64){
    float hv = h[d];
    float4 w0 = *(const float4*)(W2 + (size_t)d * 8);
    float4 w1 = *(const float4*)(W2 + (size_t)d * 8 + 4);
    acc[0] += hv * w0.x; acc[1] += hv * w0.y; acc[2] += hv * w0.z; acc[3] += hv * w0.w;
    acc[4] += hv * w1.x; acc[5] += hv * w1.y; acc[6] += hv * w1.z; acc[7] += hv * w1.w;
  }
  #pragma unroll
  for (int s = 32; s > 0; s >>= 1)
    #pragma unroll
    for (int e2 = 0; e2 < 8; ++e2)
      acc[e2] += __shfl_down(acc[e2], s, 64);
  if (lane == 0){
    int best = 0; float bv = acc[0] + b2[0]; float sv = -1e30f;
    #pragma unroll
    for (int e2 = 1; e2 < 8; ++e2){
      float v = acc[e2] + b2[e2];
      if (v > bv){ sv = bv; bv = v; best = e2; }
      else if (v > sv) sv = v;
    }
    eidx[t] = best;
    if (bv - sv < MARGIN){
      int p = atomicAdd(nflag, 1);
      if (p < MAXFLAG) flagged[p] = t;
    }
  }
}

// Exact fp32 recompute of h for flagged tokens (d-sliced across 64 blocks).
__global__ __launch_bounds__(256) void fallback_h(
    const float* __restrict__ X, const float* __restrict__ w1,
    const float* __restrict__ b1, const int* __restrict__ flagged,
    const int* __restrict__ nflag, float* __restrict__ hF)
{
  __shared__ float red[16][17];
  int nf = *nflag; if (nf > MAXFLAG) nf = MAXFLAG;
  const int d0 = blockIdx.x * 16;
  const int c = threadIdx.x & 15, kp = threadIdx.x >> 4;
  for (int s = 0; s < nf; ++s){
    const int t = flagged[s];
    const float* xr = X + (size_t)t * DD;
    float sum = 0.f;
    for (int k = kp; k < DD; k += 16)
      sum += xr[k] * w1[(size_t)k * DD + d0 + c];
    red[kp][c] = sum;
    __syncthreads();
    if (kp == 0){
      float a = 0.f;
      #pragma unroll
      for (int q = 0; q < 16; ++q) a += red[q][c];
      hF[(size_t)s * DD + d0 + c] = fmaxf(a + b1[d0 + c], 0.f);
    }
    __syncthreads();
  }
}

// Exact fp32 logits + argmax for flagged tokens; overwrites eidx.
__global__ __launch_bounds__(256) void fallback_logits(
    const float* __restrict__ hF, const float* __restrict__ W2,
    const float* __restrict__ b2, const int* __restrict__ flagged,
    const int* __restrict__ nflag, int* __restrict__ eidx)
{
  int nf = *nflag; if (nf > MAXFLAG) nf = MAXFLAG;
  const int w = threadIdx.x >> 6, lane = threadIdx.x & 63;
  for (int s = w; s < nf; s += 4){
    const float* h = hF + (size_t)s * DD;
    float acc[8] = {0,0,0,0,0,0,0,0};
    for (int d = lane; d < DD; d += 64){
      float hv = h[d];
      float4 w0 = *(const float4*)(W2 + (size_t)d * 8);
      float4 w1 = *(const float4*)(W2 + (size_t)d * 8 + 4);
      acc[0] += hv * w0.x; acc[1] += hv * w0.y; acc[2] += hv * w0.z; acc[3] += hv * w0.w;
      acc[4] += hv * w1.x; acc[5] += hv * w1.y; acc[6] += hv * w1.z; acc[7] += hv * w1.w;
    }
    #pragma unroll
    for (int sh = 32; sh > 0; sh >>= 1)
      #pragma unroll
      for (int e2 = 0; e2 < 8; ++e2)
        acc[e2] += __shfl_down(acc[e2], sh, 64);
    if (lane == 0){
      int best = 0; float bv = acc[0] + b2[0];
      #pragma unroll
      for (int e2 = 1; e2 < 8; ++e2){
        float v = acc[e2] + b2[e2];
        if (v > bv){ bv = v; best = e2; }
      }
      eidx[flagged[s]] = best;
    }
  }
}

// Count tokens per expert (block b counts expert b; no atomics, no pre-zero).
__global__ __launch_bounds__(256) void count_experts(
    const int* __restrict__ eidx, int* __restrict__ counts)
{
  __shared__ int loc[256];
  const int b = blockIdx.x;
  int c = 0;
  for (int t = threadIdx.x; t < T_TOK; t += 256) c += (eidx[t] == b);
  loc[threadIdx.x] = c;
  __syncthreads();
  for (int s = 128; s > 0; s >>= 1){
    if (threadIdx.x < s) loc[threadIdx.x] += loc[threadIdx.x + s];
    __syncthreads();
  }
  if (threadIdx.x == 0) counts[b] = loc[0];
}

__global__ void scan_offsets(const int* __restrict__ counts, int* __restrict__ offsets,
                             int* __restrict__ cursors)
{
  if (threadIdx.x == 0 && blockIdx.x == 0){
    int s = 0;
    for (int e = 0; e < EE; ++e){ offsets[e] = s; cursors[e] = s; s += counts[e]; }
    offsets[EE] = s;
  }
}

__global__ __launch_bounds__(256) void scatter_tokens(
    const int* __restrict__ eidx, int* __restrict__ cursors, int* __restrict__ perm)
{
  int t = blockIdx.x * 256 + threadIdx.x;
  if (t < T_TOK){
    int e = eidx[t];
    int p = atomicAdd(&cursors[e], 1);
    perm[p] = t;
  }
}

extern "C" void kernel_launch(void* const* d_in, const int* in_sizes, int n_in,
                              void* d_out, int out_size, void* d_ws, size_t ws_size,
                              hipStream_t stream)
{
  const float* X   = (const float*)d_in[0];
  const float* rw1 = (const float*)d_in[1];
  const float* rb1 = (const float*)d_in[2];
  const float* rw2 = (const float*)d_in[3];
  const float* rb2 = (const float*)d_in[4];
  const float* ew1 = (const float*)d_in[5];
  const float* eb1 = (const float*)d_in[6];
  const float* ew2 = (const float*)d_in[7];
  const float* eb2 = (const float*)d_in[8];
  float* out = (float*)d_out;

  char* p = (char*)d_ws;
  u16* xh   = (u16*)p;   p += (size_t)T_TOK * DD * 2;        //  4 MB
  u16* xl   = (u16*)p;   p += (size_t)T_TOK * DD * 2;        //  4 MB
  u16* B3   = (u16*)p;   p += (size_t)DD * 3072 * 2;         //  6 MB
  u16* W1t  = (u16*)p;   p += (size_t)EE * FF * DD * 2;      // 64 MB
  u16* W2t  = (u16*)p;   p += (size_t)EE * DD * FF * 2;      // 64 MB
  float* H  = (float*)p; p += (size_t)T_TOK * DD * 4;        //  8 MB
  u16* hid  = (u16*)p;   p += (size_t)T_TOK * FF * 2;        // 16 MB
  float* hF = (float*)p; p += (size_t)MAXFLAG * DD * 4;      //  4 MB
  int* eidx    = (int*)p; p += T_TOK * 4;
  int* perm    = (int*)p; p += T_TOK * 4;
  int* flagged = (int*)p; p += MAXFLAG * 4;
  int* counts  = (int*)p; p += 16 * 4;
  int* offsets = (int*)p; p += 16 * 4;
  int* cursors = (int*)p; p += 16 * 4;
  int* nflag   = (int*)p;

  // prep
  split_x<<<dim3(T_TOK), 256, 0, stream>>>(X, xh, xl, nflag);
  split_w1t<<<dim3(16, 16), 256, 0, stream>>>(rw1, B3);
  transpose_w<<<dim3(FF/64, DD/64, EE), 256, 0, stream>>>(ew1, W1t, DD, FF);
  transpose_w<<<dim3(DD/64, FF/64, EE), 256, 0, stream>>>(ew2, W2t, FF, DD);
  // router (split-bf16 MFMA, fp32-accurate H)
  gemm_bf16<0><<<dim3(DD/128, T_TOK/128, 1), 256, 0, stream>>>(
      xh, xl, B3, rb1, H, nullptr, nullptr, nullptr);
  logits_argmax<<<dim3(T_TOK), 64, 0, stream>>>(H, rw2, rb2, eidx, flagged, nflag);
  fallback_h<<<dim3(64), 256, 0, stream>>>(X, rw1, rb1, flagged, nflag, hF);
  fallback_logits<<<dim3(1), 256, 0, stream>>>(hF, rw2, rb2, flagged, nflag, eidx);
  // dispatch
  count_experts<<<dim3(EE), 256, 0, stream>>>(eidx, counts);
  scan_offsets<<<1, 64, 0, stream>>>(counts, offsets, cursors);
  scatter_tokens<<<dim3(T_TOK/256), 256, 0, stream>>>(eidx, cursors, perm);
  // experts — grid y covers the FULL token count per expert (R4 fix)
  gemm_bf16<1><<<dim3(FF/128, T_TOK/128, EE), 256, 0, stream>>>(
      xh, nullptr, W1t, eb1, nullptr, hid, perm, offsets);
  gemm_bf16<2><<<dim3(DD/64, T_TOK/128, EE), 256, 0, stream>>>(
      hid, nullptr, W2t, eb2, out, nullptr, perm, offsets);
}